// Round 14
// baseline (212.936 us; speedup 1.0000x reference)
//
#include <hip/hip_runtime.h>

typedef unsigned short u16;
typedef __attribute__((ext_vector_type(8))) short short8;
typedef __attribute__((ext_vector_type(4))) float f32x4;
typedef __attribute__((ext_vector_type(8))) unsigned short ushort8;

__device__ __forceinline__ u16 f2bf(float f) {
  unsigned u = __float_as_uint(f);
  u += 0x7FFFu + ((u >> 16) & 1u);
  return (u16)(u >> 16);
}
__device__ __forceinline__ float bf2f(u16 h) {
  return __uint_as_float(((unsigned)h) << 16);
}

#define GLD(gsrc, ldst)                                                        \
  __builtin_amdgcn_global_load_lds(                                            \
      (const __attribute__((address_space(1))) void*)(gsrc),                   \
      (__attribute__((address_space(3))) void*)(ldst), 16, 0, 0)

// B-row permutation for gemm_ln (freed-quarters contiguous)
__device__ __forceinline__ int permB(int n) {
  int wn = n >> 7, nj = (n >> 4) & 7, fr = n & 15;
  return ((nj >> 1) << 7) | (wn << 5) | ((nj & 1) << 4) | fr;
}

// ---------------- prep: everything element-wise/transpose in ONE dispatch ---
// ids 0..1023     -> Br/Bi/Cr/Ci transposes (256 tiles each)
// ids 1024..2047  -> W2 [2048][512] transpose (64x16 tiles)
// ids 2048..2559  -> W1 f32->bf16 cast
// ids 2560..10751 -> x  f32->bf16 cast
// ids 10752..10783-> bc partials: bcp[p][n] = sum_{j in chunk p} b1[j]W2[j][n]
// ids 10784..10785-> lam/lam^32/gamma constants (2 x 256 threads)
__global__ __launch_bounds__(256) void prep_all(
    const float* __restrict__ Br, const float* __restrict__ Bi,
    const float* __restrict__ Cr, const float* __restrict__ Ci,
    const float* __restrict__ W2, const float* __restrict__ W1,
    const float* __restrict__ x, const float* __restrict__ nu_log,
    const float* __restrict__ theta_log, const float* __restrict__ gamma_log,
    const float* __restrict__ b1, u16* __restrict__ BcT, u16* __restrict__ WcT,
    u16* __restrict__ W2T, u16* __restrict__ W1b, u16* __restrict__ xb,
    float* __restrict__ cst, float* __restrict__ bcp) {
  __shared__ float t[32][33];
  int id = blockIdx.x;
  if (id >= 10784) {  // constants
    int h = (id - 10784) * 256 + threadIdx.x;
    float mag = expf(-expf(nu_log[h]));
    float th = expf(theta_log[h]);
    float lr = mag * cosf(th), li = mag * sinf(th);
    cst[h] = lr;
    cst[512 + h] = li;
    float pr = lr, pi = li;
#pragma unroll
    for (int i = 0; i < 5; ++i) {  // lam^32
      float nr = pr * pr - pi * pi;
      pi = 2.f * pr * pi;
      pr = nr;
    }
    cst[1024 + h] = pr;
    cst[1536 + h] = pi;
    cst[2048 + h] = expf(gamma_log[h]);
    return;
  }
  if (id >= 10752) {  // bc partials
    int blk = id - 10752;
    int p = blk >> 1;
    int n = ((blk & 1) << 8) + threadIdx.x;
    int j0 = p << 7;
    float s = 0.f;
#pragma unroll 8
    for (int j = 0; j < 128; ++j)
      s = fmaf(b1[j0 + j], W2[(size_t)(j0 + j) * 512 + n], s);
    bcp[p * 512 + n] = s;
    return;
  }
  if (id >= 2048) {  // straight casts
    const float* src = (id >= 2560) ? x : W1;
    u16* dst = (id >= 2560) ? xb : W1b;
    int g = ((id >= 2560) ? (id - 2560) : (id - 2048)) * 256 + threadIdx.x;
    const float4* p = (const float4*)src + (size_t)g * 2;
    float4 a = p[0], b = p[1];
    ushort8 o;
    o[0] = f2bf(a.x); o[1] = f2bf(a.y); o[2] = f2bf(a.z); o[3] = f2bf(a.w);
    o[4] = f2bf(b.x); o[5] = f2bf(b.y); o[6] = f2bf(b.z); o[7] = f2bf(b.w);
    ((ushort8*)dst)[g] = o;
    return;
  }
  int which, tt;
  if (id < 1024) { which = id >> 8; tt = id & 255; }
  else { which = 5; tt = id - 1024; }
  const float* src;
  int C, bx, by;
  if (which < 4) {
    src = (which == 0) ? Br : (which == 1) ? Bi : (which == 2) ? Cr : Ci;
    C = 512; bx = tt & 15; by = tt >> 4;
  } else {
    src = W2; C = 512; bx = tt & 15; by = tt >> 4;  // by in [0,64)
  }
  int bc = bx << 5, brr = by << 5;
  int tx = threadIdx.x & 31, ty = threadIdx.x >> 5;
#pragma unroll
  for (int i = 0; i < 32; i += 8)
    t[ty + i][tx] = src[(size_t)(brr + ty + i) * C + bc + tx];
  __syncthreads();
#pragma unroll
  for (int i = 0; i < 32; i += 8) {
    int cs = bc + ty + i, rs = brr + tx;
    float v = t[tx][ty + i];
    if (which == 0)      BcT[(size_t)(2 * cs) * 512 + rs] = f2bf(v);
    else if (which == 1) BcT[(size_t)(2 * cs + 1) * 512 + rs] = f2bf(v);
    else if (which == 2) WcT[(size_t)permB(cs) * 1024 + 2 * rs] = f2bf(v);
    else if (which == 3) WcT[(size_t)permB(cs) * 1024 + 2 * rs + 1] = f2bf(-v);
    else                 W2T[(size_t)cs * 2048 + rs] = f2bf(v);
  }
}

// ids 0..1023: WcT2[i] = bf16(sum of 16 K-split partials)
// ids 1024..1025: bc[n] = b2[n] + sum_p bcp[p][n]
__global__ __launch_bounds__(256) void wc_sum(const float* __restrict__ part,
                                              u16* __restrict__ WcT2,
                                              const float* __restrict__ bp,
                                              const float* __restrict__ b2,
                                              float* __restrict__ bc) {
  int id = blockIdx.x;
  if (id < 1024) {
    int i = id * 256 + threadIdx.x;
    float s = 0.f;
#pragma unroll
    for (int p = 0; p < 16; ++p) s += part[(size_t)p * 262144 + i];
    WcT2[i] = f2bf(s);
  } else {
    int n = (id - 1024) * 256 + threadIdx.x;
    float s = b2[n];
#pragma unroll
    for (int p = 0; p < 16; ++p) s += bp[p * 512 + n];
    bc[n] = s;
  }
}

// ---------------- GEMM: 128x256 tile, BK=32 ---------------------------------
// PAD=1: +40 KiB dummy LDS -> 1 WG/CU -> grid 512 runs as 2 rounds so
// round-1's f32 store drain overlaps round-2's compute (round-13 analysis:
// G5 is last dispatch, one-round grid exposed a ~29 us store drain).
template <int EPI, int PAD = 0>
__global__ __launch_bounds__(512, 4) void gemmP(
    const u16* __restrict__ A, const u16* __restrict__ Bt, void* __restrict__ Cv,
    int M, int N, int K, int lda, int ldb, const float* __restrict__ e0,
    const float* __restrict__ e1, const float* __restrict__ e2) {
  __shared__ u16 sA[2][128 * 32];
  __shared__ u16 sB[2][256 * 32];
  __shared__ u16 sPad[PAD ? 20480 : 1];
  if (PAD) ((volatile u16*)sPad)[0] = 0;  // keep sPad allocated
  const int tid = threadIdx.x;
  const int w = tid >> 6, l = tid & 63;

  const int nby = N >> 8;
  const int nwg = gridDim.x;
  int wg = blockIdx.x;
  wg = (wg & 7) * (nwg >> 3) + (wg >> 3);
  const int n0 = (wg & (nby - 1)) << 8;
  const int m0 = (wg >> __builtin_ctz(nby)) << 7;
  const int koff = blockIdx.y * K;  // 0 except EPI5 K-split

  const int srow = tid >> 2;
  const int sslot = (tid & 3) ^ ((srow >> 1) & 3);
  const u16* gA = A + (size_t)(m0 + srow) * lda + koff + sslot * 8;
  const u16* gB = Bt + (size_t)(n0 + srow) * ldb + koff + sslot * 8;
  const size_t bstep = (size_t)128 * ldb;

#define STA(buf, kt) GLD(gA + (size_t)(kt) * 32, &sA[buf][tid * 8])
#define STB(buf, kt)                                                           \
  {                                                                            \
    GLD(gB + (size_t)(kt) * 32, &sB[buf][tid * 8]);                            \
    GLD(gB + bstep + (size_t)(kt) * 32, &sB[buf][4096 + tid * 8]);             \
  }

  const int wm = (w >> 2) << 6;  // 0/64
  const int wn = (w & 3) << 6;   // 0..192
  const int fr = l & 15;
  const int lh = l >> 4;
  const int sw8 = (lh ^ ((fr >> 1) & 3)) << 3;

  f32x4 acc[4][4] = {};
  short8 Ar[4], Bf[2];
  const int NT = K >> 5;

#define LDA(c)                                                                 \
  _Pragma("unroll") for (int mi = 0; mi < 4; ++mi)                             \
      Ar[mi] = *(const short8*)&sA[c][(wm + mi * 16 + fr) * 32 + sw8];
#define LDB2(c, njb)                                                           \
  Bf[0] = *(const short8*)&sB[c][(wn + (njb) * 16 + fr) * 32 + sw8];           \
  Bf[1] = *(const short8*)&sB[c][(wn + (njb) * 16 + 16 + fr) * 32 + sw8];
#define MM2(njb)                                                               \
  _Pragma("unroll") for (int mi = 0; mi < 4; ++mi) {                           \
    acc[mi][(njb)] = __builtin_amdgcn_mfma_f32_16x16x32_bf16(                  \
        Ar[mi], Bf[0], acc[mi][(njb)], 0, 0, 0);                               \
    acc[mi][(njb) + 1] = __builtin_amdgcn_mfma_f32_16x16x32_bf16(              \
        Ar[mi], Bf[1], acc[mi][(njb) + 1], 0, 0, 0);                           \
  }
#define BAR_LGKM()                                                             \
  __builtin_amdgcn_sched_barrier(0);                                           \
  __builtin_amdgcn_s_barrier();                                                \
  asm volatile("s_waitcnt lgkmcnt(0)" ::: "memory");                           \
  __builtin_amdgcn_sched_barrier(0);
#define TRAIL_BAR()                                                            \
  __builtin_amdgcn_sched_barrier(0);                                           \
  __builtin_amdgcn_s_barrier();

  // prologue: A0,B0 -> buf0; B1 -> buf1
  STA(0, 0);
  STB(0, 0);
  if (NT > 1) {
    STB(1, 1);
    asm volatile("s_waitcnt vmcnt(2)" ::: "memory");
  } else {
    asm volatile("s_waitcnt vmcnt(0)" ::: "memory");
  }
  __builtin_amdgcn_s_barrier();

  for (int t = 0; t < NT; ++t) {
    const int c = t & 1;
    LDA(c);
    LDB2(c, 0);
    if (t + 1 < NT) STA(c ^ 1, t + 1);
    BAR_LGKM();
    __builtin_amdgcn_s_setprio(1);
    MM2(0);
    __builtin_amdgcn_s_setprio(0);
    TRAIL_BAR();
    LDB2(c, 2);
    BAR_LGKM();
    if (t + 2 < NT) STB(c, t + 2);
    __builtin_amdgcn_s_setprio(1);
    MM2(2);
    __builtin_amdgcn_s_setprio(0);
    __builtin_amdgcn_sched_barrier(0);
    if (t + 2 < NT) {
      asm volatile("s_waitcnt vmcnt(2)" ::: "memory");
    } else if (t + 1 < NT) {
      asm volatile("s_waitcnt vmcnt(0)" ::: "memory");
    }
    __builtin_amdgcn_s_barrier();
  }

#pragma unroll
  for (int mi = 0; mi < 4; ++mi) {
#pragma unroll
    for (int nj = 0; nj < 4; ++nj) {
      const int row = m0 + wm + mi * 16 + lh * 4;
      const int col = n0 + wn + nj * 16 + fr;
#pragma unroll
      for (int q = 0; q < 4; ++q) {
        const int m = row + q;
        float v = acc[mi][nj][q];
        if constexpr (EPI == 0) {  // u interleaved: h=col>>1
          int h = col >> 1;
          float bias = (col & 1) ? e2[h] : e1[h];
          ((u16*)Cv)[(size_t)m * N + col] = f2bf(e0[h] * (v + bias));
        } else if constexpr (EPI == 3) {
          ((float*)Cv)[(size_t)m * N + col] = v + e0[col];
        } else {  // EPI 5: K-split partial
          ((float*)Cv)[((size_t)blockIdx.y * M + m) * N + col] = v;
        }
      }
    }
  }
#undef STA
#undef STB
#undef LDA
#undef LDB2
#undef MM2
#undef BAR_LGKM
#undef TRAIL_BAR
}

// ---------------- G2 + LayerNorm fused (2-phase K-loop, round-13 proven) ----
__global__ __launch_bounds__(512, 2) void gemm_ln(
    const u16* __restrict__ A, const u16* __restrict__ Bp,
    u16* __restrict__ Out, const float* __restrict__ cr,
    const float* __restrict__ ci, const float* __restrict__ lns,
    const float* __restrict__ lnb) {
  __shared__ u16 sA[2][128 * 32];
  __shared__ u16 sB[2][512 * 32];
  __shared__ float lntab[128][4][2];
  const int tid = threadIdx.x, w = tid >> 6, l = tid & 63;
  int wg = blockIdx.x;
  wg = (wg & 7) * 32 + (wg >> 3);
  const int m0 = wg << 7;

  const int ar = tid >> 2;
  const int as = (tid & 3) ^ ((ar >> 1) & 3);
  const u16* gA = A + (size_t)(m0 + ar) * 1024 + as * 8;
  const u16* gB = Bp + (size_t)ar * 1024 + as * 8;
  const size_t bstr = (size_t)128 * 1024;

#define STA(buf, kt) GLD(gA + (kt) * 32, &sA[buf][tid * 8])
#define STB(buf, kt, i) GLD(gB + bstr * (i) + (kt) * 32, &sB[buf][(i)*4096 + tid * 8])

  const int wm = (w >> 2) << 6;
  const int wi = w & 3;
  const int fr = l & 15, lh = l >> 4;
  const int swA = lh ^ (((wm + fr) >> 1) & 3);
  const int abase = ((wm + fr) << 5) + swA * 8;
  const int swB = lh ^ ((fr >> 1) & 3);
  const int bbase = (wi << 10) + (fr << 5) + swB * 8;

  f32x4 acc[4][8] = {};
  short8 Af[4], BfA0, BfA1, BfB0, BfB1;
  const int NT = 32;

#define LDAF(c)                                                                \
  _Pragma("unroll") for (int mi = 0; mi < 4; ++mi)                             \
      Af[mi] = *(const short8*)&sA[c][abase + mi * 512];
#define LDBF_A(c, j)                                                           \
  BfA0 = *(const short8*)&sB[c][((j) << 12) + bbase];                          \
  BfA1 = *(const short8*)&sB[c][((j) << 12) + bbase + 512];
#define LDBF_B(c, j)                                                           \
  BfB0 = *(const short8*)&sB[c][((j) << 12) + bbase];                          \
  BfB1 = *(const short8*)&sB[c][((j) << 12) + bbase + 512];
#define MML_A(j)                                                               \
  _Pragma("unroll") for (int mi = 0; mi < 4; ++mi) {                           \
    acc[mi][2 * (j)] = __builtin_amdgcn_mfma_f32_16x16x32_bf16(                \
        Af[mi], BfA0, acc[mi][2 * (j)], 0, 0, 0);                              \
    acc[mi][2 * (j) + 1] = __builtin_amdgcn_mfma_f32_16x16x32_bf16(            \
        Af[mi], BfA1, acc[mi][2 * (j) + 1], 0, 0, 0);                          \
  }
#define MML_B(j)                                                               \
  _Pragma("unroll") for (int mi = 0; mi < 4; ++mi) {                           \
    acc[mi][2 * (j)] = __builtin_amdgcn_mfma_f32_16x16x32_bf16(                \
        Af[mi], BfB0, acc[mi][2 * (j)], 0, 0, 0);                              \
    acc[mi][2 * (j) + 1] = __builtin_amdgcn_mfma_f32_16x16x32_bf16(            \
        Af[mi], BfB1, acc[mi][2 * (j) + 1], 0, 0, 0);                          \
  }
#define BAR_LGKM()                                                             \
  __builtin_amdgcn_sched_barrier(0);                                           \
  __builtin_amdgcn_s_barrier();                                                \
  asm volatile("s_waitcnt lgkmcnt(0)" ::: "memory");                           \
  __builtin_amdgcn_sched_barrier(0);
#define TRAIL_BAR()                                                            \
  __builtin_amdgcn_sched_barrier(0);                                           \
  __builtin_amdgcn_s_barrier();

  STA(0, 0);
  STB(0, 0, 0); STB(0, 0, 1); STB(0, 0, 2); STB(0, 0, 3);
  STB(1, 1, 0); STB(1, 1, 1);
  asm volatile("s_waitcnt vmcnt(2)" ::: "memory");
  __builtin_amdgcn_s_barrier();

  for (int t = 0; t < NT; ++t) {
    const int c = t & 1;
    LDAF(c);
    LDBF_A(c, 0);
    LDBF_B(c, 1);
    if (t + 1 < NT) {
      STA(c ^ 1, t + 1);
      STB(c ^ 1, t + 1, 2);
      STB(c ^ 1, t + 1, 3);
    }
    BAR_LGKM();
    __builtin_amdgcn_s_setprio(1);
    MML_A(0);
    MML_B(1);
    __builtin_amdgcn_s_setprio(0);
    TRAIL_BAR();
    LDBF_A(c, 2);
    LDBF_B(c, 3);
    if (t + 2 < NT) {
      STB(c, t + 2, 0);
      STB(c, t + 2, 1);
    }
    BAR_LGKM();
    __builtin_amdgcn_s_setprio(1);
    MML_A(2);
    MML_B(3);
    __builtin_amdgcn_s_setprio(0);
    __builtin_amdgcn_sched_barrier(0);
    if (t + 2 < NT) {
      asm volatile("s_waitcnt vmcnt(2)" ::: "memory");
    } else if (t + 1 < NT) {
      asm volatile("s_waitcnt vmcnt(0)" ::: "memory");
    }
    __builtin_amdgcn_s_barrier();
  }

  float bias[8], sc8[8], bi8[8];
#pragma unroll
  for (int nj = 0; nj < 8; ++nj) {
    int col = (wi << 7) + (nj << 4) + fr;
    bias[nj] = cr[col] - ci[col];
    sc8[nj] = lns[col];
    bi8[nj] = lnb[col];
  }
#pragma unroll
  for (int mi = 0; mi < 4; ++mi) {
#pragma unroll
    for (int q = 0; q < 4; ++q) {
      float s = 0.f, ss = 0.f;
#pragma unroll
      for (int nj = 0; nj < 8; ++nj) {
        float v = acc[mi][nj][q] + bias[nj];
        acc[mi][nj][q] = v;
        s += v;
        ss += v * v;
      }
#pragma unroll
      for (int mk = 1; mk <= 8; mk <<= 1) {
        s += __shfl_xor(s, mk, 64);
        ss += __shfl_xor(ss, mk, 64);
      }
      if (fr == 0) {
        int r = wm + mi * 16 + lh * 4 + q;
        lntab[r][wi][0] = s;
        lntab[r][wi][1] = ss;
      }
    }
  }
  __syncthreads();
#pragma unroll
  for (int mi = 0; mi < 4; ++mi) {
#pragma unroll
    for (int q = 0; q < 4; ++q) {
      int r = wm + mi * 16 + lh * 4 + q;
      float S = 0.f, Q = 0.f;
#pragma unroll
      for (int w2 = 0; w2 < 4; ++w2) {
        S += lntab[r][w2][0];
        Q += lntab[r][w2][1];
      }
      float mean = S * (1.f / 512.f);
      float var = Q * (1.f / 512.f) - mean * mean;
      float rstd = rsqrtf(var + 1e-6f);
#pragma unroll
      for (int nj = 0; nj < 8; ++nj) {
        int col = (wi << 7) + (nj << 4) + fr;
        float val = (acc[mi][nj][q] - mean) * rstd * sc8[nj] + bi8[nj];
        Out[(size_t)(m0 + r) * 512 + col] = f2bf(val);
      }
    }
  }
#undef STA
#undef STB
#undef LDAF
#undef LDBF_A
#undef LDBF_B
#undef MML_A
#undef MML_B
#undef BAR_LGKM
#undef TRAIL_BAR
}

// ---------------- scan: 64 chunks x 32 steps, 4 complex ch/thread ----------

__global__ __launch_bounds__(256) void scan_fin(const u16* __restrict__ u,
                                                const float* __restrict__ cst,
                                                float2* __restrict__ fin) {
  int g = blockIdx.x * 256 + threadIdx.x;
  int q = g & 127, b = (g >> 7) & 15, c = g >> 11;
  int h0 = q << 2;
  float lr[4], li[4], fr[4], fi[4];
#pragma unroll
  for (int k = 0; k < 4; ++k) {
    lr[k] = cst[h0 + k];
    li[k] = cst[512 + h0 + k];
    fr[k] = 0.f;
    fi[k] = 0.f;
  }
  const u16* p = u + (size_t)(b * 2048 + c * 32) * 1024 + (h0 << 1);
#pragma unroll 4
  for (int j = 0; j < 32; ++j) {
    ushort8 v = *(const ushort8*)p;
#pragma unroll
    for (int k = 0; k < 4; ++k) {
      float ur = bf2f(v[2 * k]), ui = bf2f(v[2 * k + 1]);
      float nr = fmaf(lr[k], fr[k], fmaf(-li[k], fi[k], ur));
      float ni = fmaf(lr[k], fi[k], fmaf(li[k], fr[k], ui));
      fr[k] = nr;
      fi[k] = ni;
    }
    p += 1024;
  }
  float2* fo = fin + (size_t)(c * 16 + b) * 512 + h0;
#pragma unroll
  for (int k = 0; k < 4; ++k) fo[k] = make_float2(fr[k], fi[k]);
}

__global__ __launch_bounds__(256) void scan_out(const u16* __restrict__ u,
                                                const float* __restrict__ cst,
                                                const float2* __restrict__ fin,
                                                u16* __restrict__ hcat) {
  int g = blockIdx.x * 256 + threadIdx.x;
  int q = g & 127, b = (g >> 7) & 15, c = g >> 11;
  int h0 = q << 2;
  float lr[4], li[4], Lr[4], Li[4], sr[4], si[4];
#pragma unroll
  for (int k = 0; k < 4; ++k) {
    lr[k] = cst[h0 + k];
    li[k] = cst[512 + h0 + k];
    Lr[k] = cst[1024 + h0 + k];
    Li[k] = cst[1536 + h0 + k];
    sr[k] = 0.f;
    si[k] = 0.f;
  }
  for (int c2 = 0; c2 < c; ++c2) {
    const float2* f = fin + (size_t)(c2 * 16 + b) * 512 + h0;
#pragma unroll
    for (int k = 0; k < 4; ++k) {
      float2 fv = f[k];
      float nr = fmaf(Lr[k], sr[k], fmaf(-Li[k], si[k], fv.x));
      float ni = fmaf(Lr[k], si[k], fmaf(Li[k], sr[k], fv.y));
      sr[k] = nr;
      si[k] = ni;
    }
  }
  size_t mb = (size_t)(b * 2048 + c * 32) * 1024 + (h0 << 1);
  const u16* p = u + mb;
  u16* o = hcat + mb;
#pragma unroll 4
  for (int j = 0; j < 32; ++j) {
    ushort8 v = *(const ushort8*)p;
    ushort8 ov;
#pragma unroll
    for (int k = 0; k < 4; ++k) {
      float ur = bf2f(v[2 * k]), ui = bf2f(v[2 * k + 1]);
      float nr = fmaf(lr[k], sr[k], fmaf(-li[k], si[k], ur));
      float ni = fmaf(lr[k], si[k], fmaf(li[k], sr[k], ui));
      sr[k] = nr;
      si[k] = ni;
      ov[2 * k] = f2bf(nr);
      ov[2 * k + 1] = f2bf(ni);
    }
    *(ushort8*)o = ov;
    p += 1024;
    o += 1024;
  }
}

// ---------------- launch ----------------
extern "C" void kernel_launch(void* const* d_in, const int* in_sizes, int n_in,
                              void* d_out, int out_size, void* d_ws,
                              size_t ws_size, hipStream_t stream) {
  const float* x   = (const float*)d_in[0];
  const float* nu  = (const float*)d_in[1];
  const float* th  = (const float*)d_in[2];
  const float* gl  = (const float*)d_in[3];
  const float* Br  = (const float*)d_in[4];
  const float* br  = (const float*)d_in[5];
  const float* Bi  = (const float*)d_in[6];
  const float* bi  = (const float*)d_in[7];
  const float* Cr  = (const float*)d_in[8];
  const float* cr  = (const float*)d_in[9];
  const float* Ci  = (const float*)d_in[10];
  const float* ci  = (const float*)d_in[11];
  const float* lns = (const float*)d_in[12];
  const float* lnb = (const float*)d_in[13];
  const float* W1  = (const float*)d_in[14];
  const float* b1  = (const float*)d_in[15];
  const float* W2  = (const float*)d_in[16];
  const float* b2  = (const float*)d_in[17];

  char* ws = (char*)d_ws;
  size_t off = 0;
  auto alloc = [&](size_t bytes) {
    char* p = ws + off;
    off += (bytes + 255) & ~(size_t)255;
    return p;
  };
  float* cst  = (float*)alloc(2560 * 4);
  u16* BcT    = (u16*)alloc((size_t)1024 * 512 * 2);
  u16* WcT    = (u16*)alloc((size_t)512 * 1024 * 2);
  u16* W2T    = (u16*)alloc((size_t)512 * 2048 * 2);
  u16* W1b    = (u16*)alloc((size_t)512 * 2048 * 2);
  u16* WcT2   = (u16*)alloc((size_t)512 * 512 * 2);
  float* bc   = (float*)alloc(512 * 4);
  float* bcp  = (float*)alloc(16 * 512 * 4);
  float* wcp  = (float*)alloc((size_t)16 * 512 * 512 * 4);
  float2* fin = (float2*)alloc((size_t)64 * 16 * 512 * 8);
  u16* xb     = (u16*)alloc((size_t)32768 * 512 * 2);
  u16* big1   = (u16*)alloc((size_t)32768 * 1024 * 2);
  u16* big2   = (u16*)alloc((size_t)32768 * 1024 * 2);
  (void)in_sizes; (void)n_in; (void)out_size; (void)ws_size;

  // prep: transposes + casts + bc partials + constants (one dispatch)
  prep_all<<<dim3(10786), dim3(256), 0, stream>>>(
      Br, Bi, Cr, Ci, W2, W1, x, nu, th, gl, b1, BcT, WcT, W2T, W1b, xb, cst,
      bcp);

  // MLP collapse precompute: 16-way K-split (K=128/WG, NT=4)
  gemmP<5><<<dim3(8, 16), dim3(512), 0, stream>>>(
      W2T, W1b, (void*)wcp, 512, 512, 128, 2048, 2048, nullptr, nullptr,
      nullptr);
  wc_sum<<<dim3(1026), dim3(256), 0, stream>>>(wcp, WcT2, bcp, b2, bc);

  // G1: u = gamma*(x@[Br|Bi] + bias) -> bf16 interleaved big1 [32768][1024]
  gemmP<0><<<dim3(1024), dim3(512), 0, stream>>>(
      xb, BcT, (void*)big1, 32768, 1024, 512, 512, 512, cst + 2048, br, bi);

  // scan (two-pass)
  scan_fin<<<dim3(512), dim3(256), 0, stream>>>((const u16*)big1, cst, fin);
  scan_out<<<dim3(512), dim3(256), 0, stream>>>((const u16*)big1, cst, fin,
                                                (u16*)big2);

  // G2 + LN fused -> ybn bf16 into xb  (2-phase K-loop, grid 256)
  gemm_ln<<<dim3(256), dim3(512), 0, stream>>>((const u16*)big2, WcT, xb, cr,
                                               ci, lns, lnb);

  // G5: out = ybn @ Wc + bc -> f32 d_out  (PAD=1: 1 WG/CU -> 2 rounds so
  // round-1's store drain hides under round-2's compute)
  gemmP<3, 1><<<dim3(512), dim3(512), 0, stream>>>(
      xb, WcT2, d_out, 32768, 512, 512, 512, 512, bc, nullptr, nullptr);
}

// Round 15
// 208.534 us; speedup vs baseline: 1.0211x; 1.0211x over previous
//
#include <hip/hip_runtime.h>

typedef unsigned short u16;
typedef __attribute__((ext_vector_type(8))) short short8;
typedef __attribute__((ext_vector_type(4))) float f32x4;
typedef __attribute__((ext_vector_type(8))) unsigned short ushort8;

__device__ __forceinline__ u16 f2bf(float f) {
  unsigned u = __float_as_uint(f);
  u += 0x7FFFu + ((u >> 16) & 1u);
  return (u16)(u >> 16);
}
__device__ __forceinline__ float bf2f(u16 h) {
  return __uint_as_float(((unsigned)h) << 16);
}

#define GLD(gsrc, ldst)                                                        \
  __builtin_amdgcn_global_load_lds(                                            \
      (const __attribute__((address_space(1))) void*)(gsrc),                   \
      (__attribute__((address_space(3))) void*)(ldst), 16, 0, 0)

// B-row permutation for gemm_ln (freed-quarters contiguous)
__device__ __forceinline__ int permB(int n) {
  int wn = n >> 7, nj = (n >> 4) & 7, fr = n & 15;
  return ((nj >> 1) << 7) | (wn << 5) | ((nj & 1) << 4) | fr;
}

// ---------------- prep: everything element-wise/transpose in ONE dispatch ---
// ids 0..1023     -> Br/Bi/Cr/Ci transposes (256 tiles each)
// ids 1024..2047  -> W2 [2048][512] transpose (64x16 tiles)
// ids 2048..2559  -> W1 f32->bf16 cast
// ids 2560..10751 -> x  f32->bf16 cast
// ids 10752..10783-> bc partials: bcp[p][n] = sum_{j in chunk p} b1[j]W2[j][n]
// ids 10784..10785-> lam/lam^32/gamma constants (2 x 256 threads)
__global__ __launch_bounds__(256) void prep_all(
    const float* __restrict__ Br, const float* __restrict__ Bi,
    const float* __restrict__ Cr, const float* __restrict__ Ci,
    const float* __restrict__ W2, const float* __restrict__ W1,
    const float* __restrict__ x, const float* __restrict__ nu_log,
    const float* __restrict__ theta_log, const float* __restrict__ gamma_log,
    const float* __restrict__ b1, u16* __restrict__ BcT, u16* __restrict__ WcT,
    u16* __restrict__ W2T, u16* __restrict__ W1b, u16* __restrict__ xb,
    float* __restrict__ cst, float* __restrict__ bcp) {
  __shared__ float t[32][33];
  int id = blockIdx.x;
  if (id >= 10784) {  // constants
    int h = (id - 10784) * 256 + threadIdx.x;
    float mag = expf(-expf(nu_log[h]));
    float th = expf(theta_log[h]);
    float lr = mag * cosf(th), li = mag * sinf(th);
    cst[h] = lr;
    cst[512 + h] = li;
    float pr = lr, pi = li;
#pragma unroll
    for (int i = 0; i < 5; ++i) {  // lam^32
      float nr = pr * pr - pi * pi;
      pi = 2.f * pr * pi;
      pr = nr;
    }
    cst[1024 + h] = pr;
    cst[1536 + h] = pi;
    cst[2048 + h] = expf(gamma_log[h]);
    return;
  }
  if (id >= 10752) {  // bc partials
    int blk = id - 10752;
    int p = blk >> 1;
    int n = ((blk & 1) << 8) + threadIdx.x;
    int j0 = p << 7;
    float s = 0.f;
#pragma unroll 8
    for (int j = 0; j < 128; ++j)
      s = fmaf(b1[j0 + j], W2[(size_t)(j0 + j) * 512 + n], s);
    bcp[p * 512 + n] = s;
    return;
  }
  if (id >= 2048) {  // straight casts
    const float* src = (id >= 2560) ? x : W1;
    u16* dst = (id >= 2560) ? xb : W1b;
    int g = ((id >= 2560) ? (id - 2560) : (id - 2048)) * 256 + threadIdx.x;
    const float4* p = (const float4*)src + (size_t)g * 2;
    float4 a = p[0], b = p[1];
    ushort8 o;
    o[0] = f2bf(a.x); o[1] = f2bf(a.y); o[2] = f2bf(a.z); o[3] = f2bf(a.w);
    o[4] = f2bf(b.x); o[5] = f2bf(b.y); o[6] = f2bf(b.z); o[7] = f2bf(b.w);
    ((ushort8*)dst)[g] = o;
    return;
  }
  int which, tt;
  if (id < 1024) { which = id >> 8; tt = id & 255; }
  else { which = 5; tt = id - 1024; }
  const float* src;
  int C, bx, by;
  if (which < 4) {
    src = (which == 0) ? Br : (which == 1) ? Bi : (which == 2) ? Cr : Ci;
    C = 512; bx = tt & 15; by = tt >> 4;
  } else {
    src = W2; C = 512; bx = tt & 15; by = tt >> 4;  // by in [0,64)
  }
  int bc = bx << 5, brr = by << 5;
  int tx = threadIdx.x & 31, ty = threadIdx.x >> 5;
#pragma unroll
  for (int i = 0; i < 32; i += 8)
    t[ty + i][tx] = src[(size_t)(brr + ty + i) * C + bc + tx];
  __syncthreads();
#pragma unroll
  for (int i = 0; i < 32; i += 8) {
    int cs = bc + ty + i, rs = brr + tx;
    float v = t[tx][ty + i];
    if (which == 0)      BcT[(size_t)(2 * cs) * 512 + rs] = f2bf(v);
    else if (which == 1) BcT[(size_t)(2 * cs + 1) * 512 + rs] = f2bf(v);
    else if (which == 2) WcT[(size_t)permB(cs) * 1024 + 2 * rs] = f2bf(v);
    else if (which == 3) WcT[(size_t)permB(cs) * 1024 + 2 * rs + 1] = f2bf(-v);
    else                 W2T[(size_t)cs * 2048 + rs] = f2bf(v);
  }
}

// ids 0..1023: WcT2[i] = bf16(sum of 16 K-split partials)
// ids 1024..1025: bc[n] = b2[n] + sum_p bcp[p][n]
__global__ __launch_bounds__(256) void wc_sum(const float* __restrict__ part,
                                              u16* __restrict__ WcT2,
                                              const float* __restrict__ bp,
                                              const float* __restrict__ b2,
                                              float* __restrict__ bc) {
  int id = blockIdx.x;
  if (id < 1024) {
    int i = id * 256 + threadIdx.x;
    float s = 0.f;
#pragma unroll
    for (int p = 0; p < 16; ++p) s += part[(size_t)p * 262144 + i];
    WcT2[i] = f2bf(s);
  } else {
    int n = (id - 1024) * 256 + threadIdx.x;
    float s = b2[n];
#pragma unroll
    for (int p = 0; p < 16; ++p) s += bp[p * 512 + n];
    bc[n] = s;
  }
}

// ---------------- GEMM: 128x256 tile, BK=32 ---------------------------------
// G5 is launched with 40960 B of DYNAMIC shared memory (not referenced in the
// body) purely to push group-segment to 90112 -> 1 WG/CU -> grid 512 runs as
// 2 rounds, so round-1's f32 store drain overlaps round-2's compute.
// (round-14 lesson: a static dummy array gets DCE'd by LDS lowering; the
// dispatch-packet dynamic size cannot be.)
template <int EPI>
__global__ __launch_bounds__(512, 4) void gemmP(
    const u16* __restrict__ A, const u16* __restrict__ Bt, void* __restrict__ Cv,
    int M, int N, int K, int lda, int ldb, const float* __restrict__ e0,
    const float* __restrict__ e1, const float* __restrict__ e2) {
  __shared__ u16 sA[2][128 * 32];
  __shared__ u16 sB[2][256 * 32];
  const int tid = threadIdx.x;
  const int w = tid >> 6, l = tid & 63;

  const int nby = N >> 8;
  const int nwg = gridDim.x;
  int wg = blockIdx.x;
  wg = (wg & 7) * (nwg >> 3) + (wg >> 3);
  const int n0 = (wg & (nby - 1)) << 8;
  const int m0 = (wg >> __builtin_ctz(nby)) << 7;
  const int koff = blockIdx.y * K;  // 0 except EPI5 K-split

  const int srow = tid >> 2;
  const int sslot = (tid & 3) ^ ((srow >> 1) & 3);
  const u16* gA = A + (size_t)(m0 + srow) * lda + koff + sslot * 8;
  const u16* gB = Bt + (size_t)(n0 + srow) * ldb + koff + sslot * 8;
  const size_t bstep = (size_t)128 * ldb;

#define STA(buf, kt) GLD(gA + (size_t)(kt) * 32, &sA[buf][tid * 8])
#define STB(buf, kt)                                                           \
  {                                                                            \
    GLD(gB + (size_t)(kt) * 32, &sB[buf][tid * 8]);                            \
    GLD(gB + bstep + (size_t)(kt) * 32, &sB[buf][4096 + tid * 8]);             \
  }

  const int wm = (w >> 2) << 6;  // 0/64
  const int wn = (w & 3) << 6;   // 0..192
  const int fr = l & 15;
  const int lh = l >> 4;
  const int sw8 = (lh ^ ((fr >> 1) & 3)) << 3;

  f32x4 acc[4][4] = {};
  short8 Ar[4], Bf[2];
  const int NT = K >> 5;

#define LDA(c)                                                                 \
  _Pragma("unroll") for (int mi = 0; mi < 4; ++mi)                             \
      Ar[mi] = *(const short8*)&sA[c][(wm + mi * 16 + fr) * 32 + sw8];
#define LDB2(c, njb)                                                           \
  Bf[0] = *(const short8*)&sB[c][(wn + (njb) * 16 + fr) * 32 + sw8];           \
  Bf[1] = *(const short8*)&sB[c][(wn + (njb) * 16 + 16 + fr) * 32 + sw8];
#define MM2(njb)                                                               \
  _Pragma("unroll") for (int mi = 0; mi < 4; ++mi) {                           \
    acc[mi][(njb)] = __builtin_amdgcn_mfma_f32_16x16x32_bf16(                  \
        Ar[mi], Bf[0], acc[mi][(njb)], 0, 0, 0);                               \
    acc[mi][(njb) + 1] = __builtin_amdgcn_mfma_f32_16x16x32_bf16(              \
        Ar[mi], Bf[1], acc[mi][(njb) + 1], 0, 0, 0);                           \
  }
#define BAR_LGKM()                                                             \
  __builtin_amdgcn_sched_barrier(0);                                           \
  __builtin_amdgcn_s_barrier();                                                \
  asm volatile("s_waitcnt lgkmcnt(0)" ::: "memory");                           \
  __builtin_amdgcn_sched_barrier(0);
#define TRAIL_BAR()                                                            \
  __builtin_amdgcn_sched_barrier(0);                                           \
  __builtin_amdgcn_s_barrier();

  // prologue: A0,B0 -> buf0; B1 -> buf1
  STA(0, 0);
  STB(0, 0);
  if (NT > 1) {
    STB(1, 1);
    asm volatile("s_waitcnt vmcnt(2)" ::: "memory");
  } else {
    asm volatile("s_waitcnt vmcnt(0)" ::: "memory");
  }
  __builtin_amdgcn_s_barrier();

  for (int t = 0; t < NT; ++t) {
    const int c = t & 1;
    LDA(c);
    LDB2(c, 0);
    if (t + 1 < NT) STA(c ^ 1, t + 1);
    BAR_LGKM();
    __builtin_amdgcn_s_setprio(1);
    MM2(0);
    __builtin_amdgcn_s_setprio(0);
    TRAIL_BAR();
    LDB2(c, 2);
    BAR_LGKM();
    if (t + 2 < NT) STB(c, t + 2);
    __builtin_amdgcn_s_setprio(1);
    MM2(2);
    __builtin_amdgcn_s_setprio(0);
    __builtin_amdgcn_sched_barrier(0);
    if (t + 2 < NT) {
      asm volatile("s_waitcnt vmcnt(2)" ::: "memory");
    } else if (t + 1 < NT) {
      asm volatile("s_waitcnt vmcnt(0)" ::: "memory");
    }
    __builtin_amdgcn_s_barrier();
  }

#pragma unroll
  for (int mi = 0; mi < 4; ++mi) {
#pragma unroll
    for (int nj = 0; nj < 4; ++nj) {
      const int row = m0 + wm + mi * 16 + lh * 4;
      const int col = n0 + wn + nj * 16 + fr;
#pragma unroll
      for (int q = 0; q < 4; ++q) {
        const int m = row + q;
        float v = acc[mi][nj][q];
        if constexpr (EPI == 0) {  // u interleaved: h=col>>1
          int h = col >> 1;
          float bias = (col & 1) ? e2[h] : e1[h];
          ((u16*)Cv)[(size_t)m * N + col] = f2bf(e0[h] * (v + bias));
        } else if constexpr (EPI == 3) {
          ((float*)Cv)[(size_t)m * N + col] = v + e0[col];
        } else {  // EPI 5: K-split partial
          ((float*)Cv)[((size_t)blockIdx.y * M + m) * N + col] = v;
        }
      }
    }
  }
#undef STA
#undef STB
#undef LDA
#undef LDB2
#undef MM2
#undef BAR_LGKM
#undef TRAIL_BAR
}

// ---------------- G2 + LayerNorm fused (2-phase K-loop, round-13 proven) ----
__global__ __launch_bounds__(512, 2) void gemm_ln(
    const u16* __restrict__ A, const u16* __restrict__ Bp,
    u16* __restrict__ Out, const float* __restrict__ cr,
    const float* __restrict__ ci, const float* __restrict__ lns,
    const float* __restrict__ lnb) {
  __shared__ u16 sA[2][128 * 32];
  __shared__ u16 sB[2][512 * 32];
  __shared__ float lntab[128][4][2];
  const int tid = threadIdx.x, w = tid >> 6, l = tid & 63;
  int wg = blockIdx.x;
  wg = (wg & 7) * 32 + (wg >> 3);
  const int m0 = wg << 7;

  const int ar = tid >> 2;
  const int as = (tid & 3) ^ ((ar >> 1) & 3);
  const u16* gA = A + (size_t)(m0 + ar) * 1024 + as * 8;
  const u16* gB = Bp + (size_t)ar * 1024 + as * 8;
  const size_t bstr = (size_t)128 * 1024;

#define STA(buf, kt) GLD(gA + (kt) * 32, &sA[buf][tid * 8])
#define STB(buf, kt, i) GLD(gB + bstr * (i) + (kt) * 32, &sB[buf][(i)*4096 + tid * 8])

  const int wm = (w >> 2) << 6;
  const int wi = w & 3;
  const int fr = l & 15, lh = l >> 4;
  const int swA = lh ^ (((wm + fr) >> 1) & 3);
  const int abase = ((wm + fr) << 5) + swA * 8;
  const int swB = lh ^ ((fr >> 1) & 3);
  const int bbase = (wi << 10) + (fr << 5) + swB * 8;

  f32x4 acc[4][8] = {};
  short8 Af[4], BfA0, BfA1, BfB0, BfB1;
  const int NT = 32;

#define LDAF(c)                                                                \
  _Pragma("unroll") for (int mi = 0; mi < 4; ++mi)                             \
      Af[mi] = *(const short8*)&sA[c][abase + mi * 512];
#define LDBF_A(c, j)                                                           \
  BfA0 = *(const short8*)&sB[c][((j) << 12) + bbase];                          \
  BfA1 = *(const short8*)&sB[c][((j) << 12) + bbase + 512];
#define LDBF_B(c, j)                                                           \
  BfB0 = *(const short8*)&sB[c][((j) << 12) + bbase];                          \
  BfB1 = *(const short8*)&sB[c][((j) << 12) + bbase + 512];
#define MML_A(j)                                                               \
  _Pragma("unroll") for (int mi = 0; mi < 4; ++mi) {                           \
    acc[mi][2 * (j)] = __builtin_amdgcn_mfma_f32_16x16x32_bf16(                \
        Af[mi], BfA0, acc[mi][2 * (j)], 0, 0, 0);                              \
    acc[mi][2 * (j) + 1] = __builtin_amdgcn_mfma_f32_16x16x32_bf16(            \
        Af[mi], BfA1, acc[mi][2 * (j) + 1], 0, 0, 0);                          \
  }
#define MML_B(j)                                                               \
  _Pragma("unroll") for (int mi = 0; mi < 4; ++mi) {                           \
    acc[mi][2 * (j)] = __builtin_amdgcn_mfma_f32_16x16x32_bf16(                \
        Af[mi], BfB0, acc[mi][2 * (j)], 0, 0, 0);                              \
    acc[mi][2 * (j) + 1] = __builtin_amdgcn_mfma_f32_16x16x32_bf16(            \
        Af[mi], BfB1, acc[mi][2 * (j) + 1], 0, 0, 0);                          \
  }
#define BAR_LGKM()                                                             \
  __builtin_amdgcn_sched_barrier(0);                                           \
  __builtin_amdgcn_s_barrier();                                                \
  asm volatile("s_waitcnt lgkmcnt(0)" ::: "memory");                           \
  __builtin_amdgcn_sched_barrier(0);
#define TRAIL_BAR()                                                            \
  __builtin_amdgcn_sched_barrier(0);                                           \
  __builtin_amdgcn_s_barrier();

  STA(0, 0);
  STB(0, 0, 0); STB(0, 0, 1); STB(0, 0, 2); STB(0, 0, 3);
  STB(1, 1, 0); STB(1, 1, 1);
  asm volatile("s_waitcnt vmcnt(2)" ::: "memory");
  __builtin_amdgcn_s_barrier();

  for (int t = 0; t < NT; ++t) {
    const int c = t & 1;
    LDAF(c);
    LDBF_A(c, 0);
    LDBF_B(c, 1);
    if (t + 1 < NT) {
      STA(c ^ 1, t + 1);
      STB(c ^ 1, t + 1, 2);
      STB(c ^ 1, t + 1, 3);
    }
    BAR_LGKM();
    __builtin_amdgcn_s_setprio(1);
    MML_A(0);
    MML_B(1);
    __builtin_amdgcn_s_setprio(0);
    TRAIL_BAR();
    LDBF_A(c, 2);
    LDBF_B(c, 3);
    if (t + 2 < NT) {
      STB(c, t + 2, 0);
      STB(c, t + 2, 1);
    }
    BAR_LGKM();
    __builtin_amdgcn_s_setprio(1);
    MML_A(2);
    MML_B(3);
    __builtin_amdgcn_s_setprio(0);
    __builtin_amdgcn_sched_barrier(0);
    if (t + 2 < NT) {
      asm volatile("s_waitcnt vmcnt(2)" ::: "memory");
    } else if (t + 1 < NT) {
      asm volatile("s_waitcnt vmcnt(0)" ::: "memory");
    }
    __builtin_amdgcn_s_barrier();
  }

  float bias[8], sc8[8], bi8[8];
#pragma unroll
  for (int nj = 0; nj < 8; ++nj) {
    int col = (wi << 7) + (nj << 4) + fr;
    bias[nj] = cr[col] - ci[col];
    sc8[nj] = lns[col];
    bi8[nj] = lnb[col];
  }
#pragma unroll
  for (int mi = 0; mi < 4; ++mi) {
#pragma unroll
    for (int q = 0; q < 4; ++q) {
      float s = 0.f, ss = 0.f;
#pragma unroll
      for (int nj = 0; nj < 8; ++nj) {
        float v = acc[mi][nj][q] + bias[nj];
        acc[mi][nj][q] = v;
        s += v;
        ss += v * v;
      }
#pragma unroll
      for (int mk = 1; mk <= 8; mk <<= 1) {
        s += __shfl_xor(s, mk, 64);
        ss += __shfl_xor(ss, mk, 64);
      }
      if (fr == 0) {
        int r = wm + mi * 16 + lh * 4 + q;
        lntab[r][wi][0] = s;
        lntab[r][wi][1] = ss;
      }
    }
  }
  __syncthreads();
#pragma unroll
  for (int mi = 0; mi < 4; ++mi) {
#pragma unroll
    for (int q = 0; q < 4; ++q) {
      int r = wm + mi * 16 + lh * 4 + q;
      float S = 0.f, Q = 0.f;
#pragma unroll
      for (int w2 = 0; w2 < 4; ++w2) {
        S += lntab[r][w2][0];
        Q += lntab[r][w2][1];
      }
      float mean = S * (1.f / 512.f);
      float var = Q * (1.f / 512.f) - mean * mean;
      float rstd = rsqrtf(var + 1e-6f);
#pragma unroll
      for (int nj = 0; nj < 8; ++nj) {
        int col = (wi << 7) + (nj << 4) + fr;
        float val = (acc[mi][nj][q] - mean) * rstd * sc8[nj] + bi8[nj];
        Out[(size_t)(m0 + r) * 512 + col] = f2bf(val);
      }
    }
  }
#undef STA
#undef STB
#undef LDAF
#undef LDBF_A
#undef LDBF_B
#undef MML_A
#undef MML_B
#undef BAR_LGKM
#undef TRAIL_BAR
}

// ---------------- scan: 64 chunks x 32 steps, 4 complex ch/thread ----------

__global__ __launch_bounds__(256) void scan_fin(const u16* __restrict__ u,
                                                const float* __restrict__ cst,
                                                float2* __restrict__ fin) {
  int g = blockIdx.x * 256 + threadIdx.x;
  int q = g & 127, b = (g >> 7) & 15, c = g >> 11;
  int h0 = q << 2;
  float lr[4], li[4], fr[4], fi[4];
#pragma unroll
  for (int k = 0; k < 4; ++k) {
    lr[k] = cst[h0 + k];
    li[k] = cst[512 + h0 + k];
    fr[k] = 0.f;
    fi[k] = 0.f;
  }
  const u16* p = u + (size_t)(b * 2048 + c * 32) * 1024 + (h0 << 1);
#pragma unroll 4
  for (int j = 0; j < 32; ++j) {
    ushort8 v = *(const ushort8*)p;
#pragma unroll
    for (int k = 0; k < 4; ++k) {
      float ur = bf2f(v[2 * k]), ui = bf2f(v[2 * k + 1]);
      float nr = fmaf(lr[k], fr[k], fmaf(-li[k], fi[k], ur));
      float ni = fmaf(lr[k], fi[k], fmaf(li[k], fr[k], ui));
      fr[k] = nr;
      fi[k] = ni;
    }
    p += 1024;
  }
  float2* fo = fin + (size_t)(c * 16 + b) * 512 + h0;
#pragma unroll
  for (int k = 0; k < 4; ++k) fo[k] = make_float2(fr[k], fi[k]);
}

__global__ __launch_bounds__(256) void scan_out(const u16* __restrict__ u,
                                                const float* __restrict__ cst,
                                                const float2* __restrict__ fin,
                                                u16* __restrict__ hcat) {
  int g = blockIdx.x * 256 + threadIdx.x;
  int q = g & 127, b = (g >> 7) & 15, c = g >> 11;
  int h0 = q << 2;
  float lr[4], li[4], Lr[4], Li[4], sr[4], si[4];
#pragma unroll
  for (int k = 0; k < 4; ++k) {
    lr[k] = cst[h0 + k];
    li[k] = cst[512 + h0 + k];
    Lr[k] = cst[1024 + h0 + k];
    Li[k] = cst[1536 + h0 + k];
    sr[k] = 0.f;
    si[k] = 0.f;
  }
  for (int c2 = 0; c2 < c; ++c2) {
    const float2* f = fin + (size_t)(c2 * 16 + b) * 512 + h0;
#pragma unroll
    for (int k = 0; k < 4; ++k) {
      float2 fv = f[k];
      float nr = fmaf(Lr[k], sr[k], fmaf(-Li[k], si[k], fv.x));
      float ni = fmaf(Lr[k], si[k], fmaf(Li[k], sr[k], fv.y));
      sr[k] = nr;
      si[k] = ni;
    }
  }
  size_t mb = (size_t)(b * 2048 + c * 32) * 1024 + (h0 << 1);
  const u16* p = u + mb;
  u16* o = hcat + mb;
#pragma unroll 4
  for (int j = 0; j < 32; ++j) {
    ushort8 v = *(const ushort8*)p;
    ushort8 ov;
#pragma unroll
    for (int k = 0; k < 4; ++k) {
      float ur = bf2f(v[2 * k]), ui = bf2f(v[2 * k + 1]);
      float nr = fmaf(lr[k], sr[k], fmaf(-li[k], si[k], ur));
      float ni = fmaf(lr[k], si[k], fmaf(li[k], sr[k], ui));
      sr[k] = nr;
      si[k] = ni;
      ov[2 * k] = f2bf(nr);
      ov[2 * k + 1] = f2bf(ni);
    }
    *(ushort8*)o = ov;
    p += 1024;
    o += 1024;
  }
}

// ---------------- launch ----------------
extern "C" void kernel_launch(void* const* d_in, const int* in_sizes, int n_in,
                              void* d_out, int out_size, void* d_ws,
                              size_t ws_size, hipStream_t stream) {
  const float* x   = (const float*)d_in[0];
  const float* nu  = (const float*)d_in[1];
  const float* th  = (const float*)d_in[2];
  const float* gl  = (const float*)d_in[3];
  const float* Br  = (const float*)d_in[4];
  const float* br  = (const float*)d_in[5];
  const float* Bi  = (const float*)d_in[6];
  const float* bi  = (const float*)d_in[7];
  const float* Cr  = (const float*)d_in[8];
  const float* cr  = (const float*)d_in[9];
  const float* Ci  = (const float*)d_in[10];
  const float* ci  = (const float*)d_in[11];
  const float* lns = (const float*)d_in[12];
  const float* lnb = (const float*)d_in[13];
  const float* W1  = (const float*)d_in[14];
  const float* b1  = (const float*)d_in[15];
  const float* W2  = (const float*)d_in[16];
  const float* b2  = (const float*)d_in[17];

  char* ws = (char*)d_ws;
  size_t off = 0;
  auto alloc = [&](size_t bytes) {
    char* p = ws + off;
    off += (bytes + 255) & ~(size_t)255;
    return p;
  };
  float* cst  = (float*)alloc(2560 * 4);
  u16* BcT    = (u16*)alloc((size_t)1024 * 512 * 2);
  u16* WcT    = (u16*)alloc((size_t)512 * 1024 * 2);
  u16* W2T    = (u16*)alloc((size_t)512 * 2048 * 2);
  u16* W1b    = (u16*)alloc((size_t)512 * 2048 * 2);
  u16* WcT2   = (u16*)alloc((size_t)512 * 512 * 2);
  float* bc   = (float*)alloc(512 * 4);
  float* bcp  = (float*)alloc(16 * 512 * 4);
  float* wcp  = (float*)alloc((size_t)16 * 512 * 512 * 4);
  float2* fin = (float2*)alloc((size_t)64 * 16 * 512 * 8);
  u16* xb     = (u16*)alloc((size_t)32768 * 512 * 2);
  u16* big1   = (u16*)alloc((size_t)32768 * 1024 * 2);
  u16* big2   = (u16*)alloc((size_t)32768 * 1024 * 2);
  (void)in_sizes; (void)n_in; (void)out_size; (void)ws_size;

  // prep: transposes + casts + bc partials + constants (one dispatch)
  prep_all<<<dim3(10786), dim3(256), 0, stream>>>(
      Br, Bi, Cr, Ci, W2, W1, x, nu, th, gl, b1, BcT, WcT, W2T, W1b, xb, cst,
      bcp);

  // MLP collapse precompute: 16-way K-split (K=128/WG, NT=4)
  gemmP<5><<<dim3(8, 16), dim3(512), 0, stream>>>(
      W2T, W1b, (void*)wcp, 512, 512, 128, 2048, 2048, nullptr, nullptr,
      nullptr);
  wc_sum<<<dim3(1026), dim3(256), 0, stream>>>(wcp, WcT2, bcp, b2, bc);

  // G1: u = gamma*(x@[Br|Bi] + bias) -> bf16 interleaved big1 [32768][1024]
  gemmP<0><<<dim3(1024), dim3(512), 0, stream>>>(
      xb, BcT, (void*)big1, 32768, 1024, 512, 512, 512, cst + 2048, br, bi);

  // scan (two-pass)
  scan_fin<<<dim3(512), dim3(256), 0, stream>>>((const u16*)big1, cst, fin);
  scan_out<<<dim3(512), dim3(256), 0, stream>>>((const u16*)big1, cst, fin,
                                                (u16*)big2);

  // G2 + LN fused -> ybn bf16 into xb  (2-phase K-loop, grid 256)
  gemm_ln<<<dim3(256), dim3(512), 0, stream>>>((const u16*)big2, WcT, xb, cr,
                                               ci, lns, lnb);

  // G5: out = ybn @ Wc + bc -> f32 d_out.
  // 40960 B dynamic LDS (unused) forces 1 WG/CU -> 2 rounds -> round-1's
  // store drain hides under round-2's compute.
  gemmP<3><<<dim3(512), dim3(512), 40960, stream>>>(
      xb, WcT2, d_out, 32768, 512, 512, 512, 512, bc, nullptr, nullptr);
}